// Round 13
// baseline (565.147 us; speedup 1.0000x reference)
//
#include <hip/hip_runtime.h>
#include <math.h>

#define NNODES 8192
#define CAP 1024   // max neighbors/row in CSR (true max ~500 at 5% density)
#define KSPLIT 4
#define KCHUNK (NNODES / KSPLIT)

typedef __attribute__((ext_vector_type(8))) short bf16x8;
typedef __attribute__((ext_vector_type(4))) float f32x4;
typedef unsigned short ushort_t;

__device__ inline unsigned short f2bf(float x) {
    unsigned u = __builtin_bit_cast(unsigned, x);
    u += 0x7fffu + ((u >> 16) & 1u);   // RNE
    return (unsigned short)(u >> 16);
}

#define GLOAD_LDS16(g, l)                                                      \
    __builtin_amdgcn_global_load_lds(                                          \
        (const __attribute__((address_space(1))) void*)(g),                    \
        (__attribute__((address_space(3))) void*)(l), 16, 0, 0)

// Stage a [ROWS][64]-bf16 tile into LDS, XOR-swizzled via global src.
template <int ROWS>
__device__ inline void stage_tile(ushort_t* lds, const ushort_t* g, size_t ld, int tid)
{
#pragma unroll
    for (int c = 0; c < ROWS / 32; ++c) {
        int row = c * 32 + (tid >> 3);
        int lch = (tid & 7) ^ (row & 7);
        GLOAD_LDS16(g + (size_t)row * ld + lch * 8, lds + (size_t)c * 2048 + tid * 8);
    }
}

__device__ inline int swz_off(int row, int kc) {
    return row * 64 + ((kc ^ (row & 7)) * 8);
}

// BK=32 variants (64B rows, 4 chunks of 16B; chunk ^= row&3 -> 2-way free)
__device__ inline int swz32(int row, int kc) {
    return row * 32 + ((kc ^ (row & 3)) * 8);
}

// ---------------------------------------------------------------------------
// f32 tiled GEMM (layer-2 h1p@W2 only)
// ---------------------------------------------------------------------------
__global__ __launch_bounds__(256) void gemm64(const float* __restrict__ A,
                                              const float* __restrict__ B,
                                              float* __restrict__ C,
                                              int M, int N, int K)
{
    __shared__ float sA[16][68];
    __shared__ float sB[16][68];

    const int tid = threadIdx.x;
    const int tx = tid & 15, ty = tid >> 4;
    const int bm = blockIdx.x * 64, bn = blockIdx.y * 64;

    float acc[4][4] = {};

    for (int k0 = 0; k0 < K; k0 += 16) {
        for (int l = tid; l < 64 * 16; l += 256) {
            int m = l >> 4, k = l & 15;
            sA[k][m] = A[(size_t)(bm + m) * K + k0 + k];
        }
        for (int l = tid; l < 16 * 64; l += 256) {
            int k = l >> 6, n = l & 63;
            sB[k][n] = B[(size_t)(k0 + k) * N + bn + n];
        }
        __syncthreads();
#pragma unroll
        for (int k = 0; k < 16; ++k) {
            float a[4], b[4];
#pragma unroll
            for (int i = 0; i < 4; ++i) a[i] = sA[k][ty * 4 + i];
#pragma unroll
            for (int j = 0; j < 4; ++j) b[j] = sB[k][tx * 4 + j];
#pragma unroll
            for (int i = 0; i < 4; ++i)
#pragma unroll
                for (int j = 0; j < 4; ++j) acc[i][j] += a[i] * b[j];
        }
        __syncthreads();
    }

#pragma unroll
    for (int i = 0; i < 4; ++i) {
        float4 v = make_float4(acc[i][0], acc[i][1], acc[i][2], acc[i][3]);
        *(float4*)&C[(size_t)(bm + ty * 4 + i) * N + bn + tx * 4] = v;
    }
}

// ---------------------------------------------------------------------------
// s = h @ a_self, n = h @ a_neigh  (one wave per row) — layer 1 (D=512)
// ---------------------------------------------------------------------------
template <int D>
__global__ __launch_bounds__(256) void sn_kernel(const float* __restrict__ h,
                                                 const float* __restrict__ a_s,
                                                 const float* __restrict__ a_n,
                                                 float* __restrict__ sv,
                                                 float* __restrict__ nv)
{
    const int row = (blockIdx.x * 256 + threadIdx.x) >> 6;
    const int lane = threadIdx.x & 63;
    if (row >= NNODES) return;
    const float* hr = h + (size_t)row * D;
    float a0 = 0.f, a1 = 0.f;
#pragma unroll
    for (int k = lane; k < D; k += 64) {
        float hv = hr[k];
        a0 += hv * a_s[k];
        a1 += hv * a_n[k];
    }
#pragma unroll
    for (int o = 32; o; o >>= 1) {
        a0 += __shfl_down(a0, o);
        a1 += __shfl_down(a1, o);
    }
    if (lane == 0) { sv[row] = a0; nv[row] = a1; }
}

// ---------------------------------------------------------------------------
// Layer-2 sn + fused bf16 cast: reads each h row once, emits sv/nv AND h2b.
// ---------------------------------------------------------------------------
__global__ __launch_bounds__(256) void sn128_fused(const float* __restrict__ h,
                                                   const float* __restrict__ a_s,
                                                   const float* __restrict__ a_n,
                                                   float* __restrict__ sv,
                                                   float* __restrict__ nv,
                                                   ushort_t* __restrict__ h2b)
{
    const int row = (blockIdx.x * 256 + threadIdx.x) >> 6;
    const int lane = threadIdx.x & 63;
    if (row >= NNODES) return;
    const float* hr = h + (size_t)row * 128;
    float v0 = hr[lane], v1 = hr[lane + 64];
    h2b[(size_t)row * 128 + lane]      = f2bf(v0);
    h2b[(size_t)row * 128 + lane + 64] = f2bf(v1);
    float a0 = v0 * a_s[lane] + v1 * a_s[lane + 64];
    float a1 = v0 * a_n[lane] + v1 * a_n[lane + 64];
#pragma unroll
    for (int o = 32; o; o >>= 1) {
        a0 += __shfl_down(a0, o);
        a1 += __shfl_down(a1, o);
    }
    if (lane == 0) { sv[row] = a0; nv[row] = a1; }
}

// ---------------------------------------------------------------------------
// adj-ONLY scan. Wave per row, ballot compaction (scan wall frozen).
// ---------------------------------------------------------------------------
__global__ __launch_bounds__(256) void build_cols(const float* __restrict__ adj,
                                                  unsigned short* __restrict__ cols,
                                                  int* __restrict__ nnzs)
{
    const int lane = threadIdx.x & 63;
    const int row = blockIdx.x * 4 + (threadIdx.x >> 6);
    const float4* arow = (const float4*)(adj + (size_t)row * NNODES);
    const size_t base = (size_t)row * CAP;
    const unsigned long long below = (1ull << lane) - 1ull;

    int off = 0;
    for (int c4 = 0; c4 < NNODES / 4; c4 += 64) {
        float4 a = arow[c4 + lane];
#pragma unroll
        for (int e = 0; e < 4; ++e) {
            float ae = (&a.x)[e];
            unsigned long long mask = __ballot(ae > 0.f);
            if (ae > 0.f) {
                int pos = off + __popcll(mask & below);
                if (pos < CAP)
                    cols[base + pos] = (unsigned short)((c4 + lane) * 4 + e);
            }
            off += __popcll(mask);
        }
    }
    if (lane == 0) nnzs[row] = off;
}

// ---------------------------------------------------------------------------
// Standalone M-value gather: vals[i][k] = M[i, cols[i][k]]. TLP-rich.
// ---------------------------------------------------------------------------
__global__ __launch_bounds__(256) void gather_vals(const unsigned short* __restrict__ cols,
                                                   const float* __restrict__ Mm,
                                                   const int* __restrict__ nnzs,
                                                   float* __restrict__ vals)
{
    const int i = blockIdx.x;
    const int nnz = min(nnzs[i], CAP);
    const size_t base = (size_t)i * CAP;
    const size_t rowoff = (size_t)i * NNODES;
    for (int k = threadIdx.x; k < nnz; k += 256)
        vals[base + k] = Mm[rowoff + cols[base + k]];
}

// ---------------------------------------------------------------------------
// Row softmax on CSR; dense bf16 P row in LDS, coalesced stream-out.
// ---------------------------------------------------------------------------
__global__ __launch_bounds__(256) void softmax_dense(const unsigned short* __restrict__ cols,
                                                     const float* __restrict__ vals,
                                                     const int* __restrict__ nnzs,
                                                     const float* __restrict__ sv,
                                                     const float* __restrict__ nv,
                                                     ushort_t* __restrict__ P)
{
    constexpr int NT = 256;
    __shared__ ushort_t drow[NNODES];
    __shared__ unsigned short scol[CAP];
    __shared__ float sp[CAP];
    __shared__ float reds[4];
    __shared__ float fb;

    const int tid = threadIdx.x;
    const int i = blockIdx.x;
    const int nnz = min(nnzs[i], CAP);
    const float si = sv[i];
    const size_t base = (size_t)i * CAP;

#pragma unroll
    for (int k = 0; k < NNODES / 8 / NT; ++k)
        ((uint4*)drow)[k * NT + tid] = (uint4){0u, 0u, 0u, 0u};

    float lmax = -3.0e38f;
    for (int k = tid; k < nnz; k += NT) {
        unsigned short c = cols[base + k];
        float e = (si + nv[c]) * vals[base + k];
        e = e > 0.f ? e : 0.2f * e;
        scol[k] = c;
        sp[k] = e;
        lmax = fmaxf(lmax, e);
    }
#pragma unroll
    for (int o = 32; o; o >>= 1) lmax = fmaxf(lmax, __shfl_down(lmax, o));
    if ((tid & 63) == 0) reds[tid >> 6] = lmax;
    __syncthreads();
    if (tid == 0) fb = fmaxf(fmaxf(reds[0], reds[1]), fmaxf(reds[2], reds[3]));
    __syncthreads();
    const float m = fb;

    float lsum = 0.f;
    for (int k = tid; k < nnz; k += NT) {
        float p = expf(sp[k] - m);
        sp[k] = p;
        lsum += p;
    }
#pragma unroll
    for (int o = 32; o; o >>= 1) lsum += __shfl_down(lsum, o);
    if ((tid & 63) == 0) reds[tid >> 6] = lsum;
    __syncthreads();
    if (tid == 0) fb = reds[0] + reds[1] + reds[2] + reds[3];
    __syncthreads();
    const float inv = 1.0f / fb;

    for (int k = tid; k < nnz; k += NT)
        drow[scol[k]] = f2bf(sp[k] * inv);
    __syncthreads();

    uint4* dst = (uint4*)(P + (size_t)i * NNODES);
#pragma unroll
    for (int k = 0; k < NNODES / 8 / NT; ++k)
        dst[k * NT + tid] = ((const uint4*)drow)[k * NT + tid];
}

// ---------------------------------------------------------------------------
// Generic transpose-cast: in [R][C] f32 -> out [C][R] bf16.
// ---------------------------------------------------------------------------
__global__ __launch_bounds__(256) void tcast(const float* __restrict__ in,
                                             ushort_t* __restrict__ out,
                                             int R, int C)
{
    __shared__ ushort_t t[64][66];
    const int bi = blockIdx.x;
    const int bj = blockIdx.y;
    const int c = threadIdx.x & 63, r4 = threadIdx.x >> 6;
#pragma unroll
    for (int i = 0; i < 16; ++i) {
        int r = i * 4 + r4;
        t[r][c] = f2bf(in[(size_t)(bi * 64 + r) * C + bj * 64 + c]);
    }
    __syncthreads();
#pragma unroll
    for (int i = 0; i < 16; ++i) {
        int r = i * 4 + r4;
        out[(size_t)(bj * 64 + r) * R + bi * 64 + c] = t[c][r];
    }
}

// ---------------------------------------------------------------------------
// flat f32 -> bf16 cast (4 elems/thread) — layer-1 x only
// ---------------------------------------------------------------------------
__global__ __launch_bounds__(256) void cast_bf(const float* __restrict__ in,
                                               ushort_t* __restrict__ out, int n4)
{
    int i = blockIdx.x * 256 + threadIdx.x;
    if (i >= n4) return;
    float4 v = ((const float4*)in)[i];
    ushort_t o[4] = { f2bf(v.x), f2bf(v.y), f2bf(v.z), f2bf(v.w) };
    *(uint2*)&out[(size_t)i * 4] = *(uint2*)o;
}

// ---------------------------------------------------------------------------
// Generic bf16 MFMA GEMM (x@W1): C = A @ BT^T. BM=BN=128, BK=64.
// ---------------------------------------------------------------------------
template <int ELU>
__global__ __launch_bounds__(256) void gemm_mfma(const ushort_t* __restrict__ A,
                                                 const ushort_t* __restrict__ BT,
                                                 float* __restrict__ C,
                                                 int N, int K)
{
    __shared__ __align__(16) ushort_t At[128 * 64];
    __shared__ __align__(16) ushort_t Bt[128 * 64];

    const int tid = threadIdx.x;
    const int wid = tid >> 6, lane = tid & 63;
    const int wr = wid >> 1, wc = wid & 1;
    const int bm = blockIdx.x * 128;
    const int bn = blockIdx.y * 128;

    f32x4 acc[4][4] = {};

    for (int k0 = 0; k0 < K; k0 += 64) {
        stage_tile<128>(At, A + (size_t)bm * K + k0, K, tid);
        stage_tile<128>(Bt, BT + (size_t)bn * K + k0, K, tid);
        __syncthreads();
#pragma unroll
        for (int kk = 0; kk < 2; ++kk) {
            const int kc = kk * 4 + (lane >> 4);
            bf16x8 af[4], bfr[4];
#pragma unroll
            for (int m = 0; m < 4; ++m) {
                int r = wr * 64 + m * 16 + (lane & 15);
                af[m] = *(const bf16x8*)&At[swz_off(r, kc)];
            }
#pragma unroll
            for (int n = 0; n < 4; ++n) {
                int r = wc * 64 + n * 16 + (lane & 15);
                bfr[n] = *(const bf16x8*)&Bt[swz_off(r, kc)];
            }
#pragma unroll
            for (int m = 0; m < 4; ++m)
#pragma unroll
                for (int n = 0; n < 4; ++n)
                    acc[m][n] = __builtin_amdgcn_mfma_f32_16x16x32_bf16(af[m], bfr[n], acc[m][n], 0, 0, 0);
        }
        __syncthreads();
    }

#pragma unroll
    for (int m = 0; m < 4; ++m)
#pragma unroll
        for (int n = 0; n < 4; ++n)
#pragma unroll
            for (int r_ = 0; r_ < 4; ++r_) {
                int row = bm + wr * 64 + m * 16 + (lane >> 4) * 4 + r_;
                int col = bn + wc * 64 + n * 16 + (lane & 15);
                float v = acc[m][n][r_];
                if (ELU) v = v > 0.f ? v : expm1f(v);
                C[(size_t)row * N + col] = v;
            }
}

// ---------------------------------------------------------------------------
// Split-K PV GEMM, 2-phase double-buffered (T3-minimum recipe, m248v2):
// BK=32 so LDS stays 32 KB (2 bufs) -> 4 blk/CU preserved (m132 trap avoided).
// Per K-step: issue STAGE(next) BEFORE computing current; ONE barrier/step
// (its implicit vmcnt(0) lands after the MFMA window -> prefetch hidden).
// Race-safe: buf^1 was last read before the previous barrier. FP order
// identical to r12 (ascending k, same fragment layout).
// ---------------------------------------------------------------------------
__global__ __launch_bounds__(256) void gemm_pv_ksplit(const ushort_t* __restrict__ P,
                                                      const ushort_t* __restrict__ hbT,
                                                      float* __restrict__ part)
{
    __shared__ __align__(16) ushort_t At[2][128 * 32];   // 8 KB each
    __shared__ __align__(16) ushort_t Bt[2][128 * 32];

    const int tid = threadIdx.x;
    const int wid = tid >> 6, lane = tid & 63;
    const int wr = wid >> 1, wc = wid & 1;
    const int bm = blockIdx.x * 128;
    const int bn = blockIdx.y * 128;
    const int kz = blockIdx.z;
    const int kbeg = kz * KCHUNK;

    const ushort_t* gA = P + (size_t)bm * NNODES + kbeg;
    const ushort_t* gB = hbT + (size_t)bn * NNODES + kbeg;

    f32x4 acc[4][4] = {};

    // stage K-step t (32 k) into buffer b: 128 rows x 64 B, 2 rounds of 64 rows
#define STAGE32(t, b)                                                          \
    do {                                                                       \
        _Pragma("unroll")                                                      \
        for (int c = 0; c < 2; ++c) {                                          \
            int row = c * 64 + (tid >> 2);                                     \
            int lch = (tid & 3) ^ (row & 3);                                   \
            GLOAD_LDS16(gA + (size_t)row * NNODES + (t) * 32 + lch * 8,        \
                        &At[b][c * 2048 + tid * 8]);                           \
            GLOAD_LDS16(gB + (size_t)row * NNODES + (t) * 32 + lch * 8,        \
                        &Bt[b][c * 2048 + tid * 8]);                           \
        }                                                                      \
    } while (0)

    constexpr int NSTEP = KCHUNK / 32;   // 64
    int cur = 0;

    STAGE32(0, 0);
    __syncthreads();                     // drains prologue loads

    for (int t = 0; t < NSTEP; ++t) {
        if (t + 1 < NSTEP) STAGE32(t + 1, cur ^ 1);   // prefetch issued first

        const ushort_t* A_ = At[cur];
        const ushort_t* B_ = Bt[cur];
        const int kc = lane >> 4;        // 4 chunks over BK=32
        bf16x8 af[4], bfr[4];
#pragma unroll
        for (int m = 0; m < 4; ++m) {
            int r = wr * 64 + m * 16 + (lane & 15);
            af[m] = *(const bf16x8*)&A_[swz32(r, kc)];
        }
#pragma unroll
        for (int n = 0; n < 4; ++n) {
            int r = wc * 64 + n * 16 + (lane & 15);
            bfr[n] = *(const bf16x8*)&B_[swz32(r, kc)];
        }
#pragma unroll
        for (int m = 0; m < 4; ++m)
#pragma unroll
            for (int n = 0; n < 4; ++n)
                acc[m][n] = __builtin_amdgcn_mfma_f32_16x16x32_bf16(af[m], bfr[n], acc[m][n], 0, 0, 0);

        __syncthreads();                 // one barrier/step: drains prefetch,
        cur ^= 1;                        // guards buf reuse next iteration
    }
#undef STAGE32

    float* dst = part + (size_t)kz * NNODES * 512;
#pragma unroll
    for (int m = 0; m < 4; ++m)
#pragma unroll
        for (int n = 0; n < 4; ++n)
#pragma unroll
            for (int r_ = 0; r_ < 4; ++r_) {
                int row = bm + wr * 64 + m * 16 + (lane >> 4) * 4 + r_;
                int col = bn + wc * 64 + n * 16 + (lane & 15);
                dst[(size_t)row * 512 + col] = acc[m][n][r_];
            }
}

// ---------------------------------------------------------------------------
// h1p = elu(sum_kz part[kz])  — 4 reads + 1 write, float4.
// ---------------------------------------------------------------------------
__global__ __launch_bounds__(256) void reduce_elu(const float* __restrict__ part,
                                                  float* __restrict__ out)
{
    const size_t S = (size_t)NNODES * 512 / 4;
    size_t i = (size_t)blockIdx.x * 256 + threadIdx.x;
    if (i >= S) return;
    const float4* p = (const float4*)part;
    float4 a = p[i], b = p[i + S], c = p[i + 2 * S], d = p[i + 3 * S];
    float4 r;
    r.x = a.x + b.x + c.x + d.x;
    r.y = a.y + b.y + c.y + d.y;
    r.z = a.z + b.z + c.z + d.z;
    r.w = a.w + b.w + c.w + d.w;
    r.x = r.x > 0.f ? r.x : expm1f(r.x);
    r.y = r.y > 0.f ? r.y : expm1f(r.y);
    r.z = r.z > 0.f ? r.z : expm1f(r.z);
    r.w = r.w > 0.f ? r.w : expm1f(r.w);
    ((float4*)out)[i] = r;
}

// ---------------------------------------------------------------------------
// A_pred = sigmoid(z @ z^T), symmetry-halved with coalesced mirrored emit.
// ---------------------------------------------------------------------------
__global__ __launch_bounds__(256) void apred_mfma(const ushort_t* __restrict__ zb,
                                                  float* __restrict__ out)
{
    const int bx = blockIdx.x, by = blockIdx.y;
    if (bx > by) return;

    __shared__ __align__(16) char smem[4 * 64 * 68 * 4];
    ushort_t* At = (ushort_t*)smem;
    ushort_t* Bt = (ushort_t*)(smem + 16384);

    const int tid = threadIdx.x;
    const int wid = tid >> 6, lane = tid & 63;
    const int wr = wid >> 1, wc = wid & 1;
    const int bm = bx * 128;
    const int bn = by * 128;

    f32x4 acc[4][4] = {};

#pragma unroll
    for (int k0 = 0; k0 < 128; k0 += 64) {
        stage_tile<128>(At, zb + (size_t)bm * 128 + k0, 128, tid);
        stage_tile<128>(Bt, zb + (size_t)bn * 128 + k0, 128, tid);
        __syncthreads();
#pragma unroll
        for (int kk = 0; kk < 2; ++kk) {
            const int kc = kk * 4 + (lane >> 4);
            bf16x8 af[4], bfr[4];
#pragma unroll
            for (int m = 0; m < 4; ++m) {
                int r = wr * 64 + m * 16 + (lane & 15);
                af[m] = *(const bf16x8*)&At[swz_off(r, kc)];
            }
#pragma unroll
            for (int n = 0; n < 4; ++n) {
                int r = wc * 64 + n * 16 + (lane & 15);
                bfr[n] = *(const bf16x8*)&Bt[swz_off(r, kc)];
            }
#pragma unroll
            for (int m = 0; m < 4; ++m)
#pragma unroll
                for (int n = 0; n < 4; ++n)
                    acc[m][n] = __builtin_amdgcn_mfma_f32_16x16x32_bf16(af[m], bfr[n], acc[m][n], 0, 0, 0);
        }
        __syncthreads();
    }

    float* cb = (float*)smem + (size_t)wid * 64 * 68;
#pragma unroll
    for (int m = 0; m < 4; ++m)
#pragma unroll
        for (int n = 0; n < 4; ++n)
#pragma unroll
            for (int r_ = 0; r_ < 4; ++r_) {
                int rl = m * 16 + (lane >> 4) * 4 + r_;
                int cl = n * 16 + (lane & 15);
                float v = acc[m][n][r_];
                cb[rl * 68 + cl] = 1.0f / (1.0f + expf(-v));
            }

    const int rowbase = bm + wr * 64;
    const int colbase = bn + wc * 64;

#pragma unroll
    for (int j = 0; j < 16; ++j) {
        int rl = j * 4 + (lane >> 4);
        int c4 = (lane & 15) * 4;
        float4 v = *(const float4*)&cb[rl * 68 + c4];
        *(float4*)&out[(size_t)(rowbase + rl) * NNODES + colbase + c4] = v;
    }

    if (bx < by) {
#pragma unroll
        for (int j = 0; j < 16; ++j) {
            int rl2 = j * 4 + (lane >> 4);
            int c4 = (lane & 15) * 4;
            float4 v;
            v.x = cb[(c4 + 0) * 68 + rl2];
            v.y = cb[(c4 + 1) * 68 + rl2];
            v.z = cb[(c4 + 2) * 68 + rl2];
            v.w = cb[(c4 + 3) * 68 + rl2];
            *(float4*)&out[(size_t)(colbase + rl2) * NNODES + rowbase + c4] = v;
        }
    }
}

// ---------------------------------------------------------------------------
// Layer-2 CSR attention: probs f32, PV gather from bf16 h table (2 MiB).
// ---------------------------------------------------------------------------
__global__ __launch_bounds__(256) void attn2_csr(const unsigned short* __restrict__ cols,
                                                 const float* __restrict__ vals,
                                                 const int* __restrict__ nnzs,
                                                 const float* __restrict__ sv,
                                                 const float* __restrict__ nv,
                                                 const ushort_t* __restrict__ h2b,
                                                 float* __restrict__ out)
{
    constexpr int NT = 256;
    __shared__ unsigned short scol[CAP];
    __shared__ float sp[CAP];
    __shared__ float reds[4];
    __shared__ float fb;
    __shared__ float2 part[NT];

    const int tid = threadIdx.x;
    const int i = blockIdx.x;
    const int nnz = min(nnzs[i], CAP);
    const float si = sv[i];
    const size_t base = (size_t)i * CAP;

    float lmax = -3.0e38f;
    for (int k = tid; k < nnz; k += NT) {
        unsigned short c = cols[base + k];
        float e = (si + nv[c]) * vals[base + k];
        e = e > 0.f ? e : 0.2f * e;
        scol[k] = c;
        sp[k] = e;
        lmax = fmaxf(lmax, e);
    }
#pragma unroll
    for (int o = 32; o; o >>= 1) lmax = fmaxf(lmax, __shfl_down(lmax, o));
    if ((tid & 63) == 0) reds[tid >> 6] = lmax;
    __syncthreads();
    if (tid == 0) fb = fmaxf(fmaxf(reds[0], reds[1]), fmaxf(reds[2], reds[3]));
    __syncthreads();
    const float m = fb;

    float lsum = 0.f;
    for (int k = tid; k < nnz; k += NT) {
        float p = expf(sp[k] - m);
        sp[k] = p;
        lsum += p;
    }
#pragma unroll
    for (int o = 32; o; o >>= 1) lsum += __shfl_down(lsum, o);
    if ((tid & 63) == 0) reds[tid >> 6] = lsum;
    __syncthreads();
    if (tid == 0) fb = reds[0] + reds[1] + reds[2] + reds[3];
    __syncthreads();
    const float inv = 1.0f / fb;

    const int g = tid >> 6, lane = tid & 63;
    float ax = 0.f, ay = 0.f;
    for (int k = g; k < nnz; k += 4) {
        float pj = sp[k];
        unsigned hv = *(const unsigned*)&h2b[(size_t)scol[k] * 128 + lane * 2];
        ax += pj * __builtin_bit_cast(float, hv << 16);
        ay += pj * __builtin_bit_cast(float, hv & 0xffff0000u);
    }
    part[tid] = make_float2(ax, ay);
    __syncthreads();
    if (tid < 64) {
        float2 r0 = part[tid], r1 = part[tid + 64], r2 = part[tid + 128], r3 = part[tid + 192];
        float vx = (r0.x + r1.x + r2.x + r3.x) * inv;
        float vy = (r0.y + r1.y + r2.y + r3.y) * inv;
        out[(size_t)i * 128 + tid * 2]     = vx > 0.f ? vx : expm1f(vx);
        out[(size_t)i * 128 + tid * 2 + 1] = vy > 0.f ? vy : expm1f(vy);
    }
}

// ---------------------------------------------------------------------------
// z = h / max(||h||,1e-12); also writes bf16 copy zb
// ---------------------------------------------------------------------------
__global__ __launch_bounds__(256) void norm_kernel(const float* __restrict__ h,
                                                   float* __restrict__ z,
                                                   ushort_t* __restrict__ zb)
{
    const int row = (blockIdx.x * 256 + threadIdx.x) >> 6;
    const int lane = threadIdx.x & 63;
    if (row >= NNODES) return;
    const float* hr = h + (size_t)row * 128;
    float v0 = hr[lane], v1 = hr[lane + 64];
    float ss = v0 * v0 + v1 * v1;
#pragma unroll
    for (int o = 32; o; o >>= 1) ss += __shfl_down(ss, o);
    ss = __shfl(ss, 0);
    float invn = 1.0f / fmaxf(sqrtf(ss), 1e-12f);
    float z0 = v0 * invn, z1 = v1 * invn;
    z[(size_t)row * 128 + lane]      = z0;
    z[(size_t)row * 128 + lane + 64] = z1;
    zb[(size_t)row * 128 + lane]      = f2bf(z0);
    zb[(size_t)row * 128 + lane + 64] = f2bf(z1);
}

// ---------------------------------------------------------------------------
// Fallback dense attention (round-1 path) — only if ws is too small.
// ---------------------------------------------------------------------------
template <int D>
__global__ __launch_bounds__(256) void attn_kernel(const float* __restrict__ adj,
                                                   const float* __restrict__ Mm,
                                                   const float* __restrict__ sv,
                                                   const float* __restrict__ nv,
                                                   const float* __restrict__ h,
                                                   float* __restrict__ out)
{
    constexpr int NT = 256;
    constexpr int DCAP = 2048;
    __shared__ float pbuf[NNODES];
    __shared__ int   idxb[DCAP];
    __shared__ int   cnts[NT];
    __shared__ float reds[4];
    __shared__ float fbcast;
    __shared__ int   totc;

    const int tid = threadIdx.x;
    const int i = blockIdx.x;
    const size_t rowoff = (size_t)i * NNODES;
    const float si = sv[i];

    float lmax = -3.0e38f;
    for (int j = tid; j < NNODES; j += NT) {
        float a = adj[rowoff + j];
        float val = -9.0e15f;
        if (a > 0.f) {
            float e = (si + nv[j]) * Mm[rowoff + j];
            val = e > 0.f ? e : 0.2f * e;
            lmax = fmaxf(lmax, val);
        }
        pbuf[j] = val;
    }
#pragma unroll
    for (int o = 32; o; o >>= 1) lmax = fmaxf(lmax, __shfl_down(lmax, o));
    if ((tid & 63) == 0) reds[tid >> 6] = lmax;
    __syncthreads();
    if (tid == 0) fbcast = fmaxf(fmaxf(reds[0], reds[1]), fmaxf(reds[2], reds[3]));
    __syncthreads();
    const float m = fbcast;

    float lsum = 0.f;
    int myc = 0;
    for (int j = tid; j < NNODES; j += NT) {
        float v = pbuf[j];
        float p = (v > -8.9e15f) ? expf(v - m) : 0.f;
        pbuf[j] = p;
        lsum += p;
        if (p > 0.f) myc++;
    }
#pragma unroll
    for (int o = 32; o; o >>= 1) lsum += __shfl_down(lsum, o);
    if ((tid & 63) == 0) reds[tid >> 6] = lsum;
    cnts[tid] = myc;
    __syncthreads();
    if (tid == 0) {
        fbcast = reds[0] + reds[1] + reds[2] + reds[3];
        int run = 0;
        for (int t = 0; t < NT; ++t) { int c = cnts[t]; cnts[t] = run; run += c; }
        totc = run;
    }
    __syncthreads();
    const float inv = 1.0f / fbcast;
    const int nnz = totc;

    if (nnz <= DCAP) {
        int off = cnts[tid];
        for (int j = tid; j < NNODES; j += NT)
            if (pbuf[j] > 0.f) idxb[off++] = j;
    }
    __syncthreads();

    if constexpr (D == 512) {
        const int c = tid;
        float acc0 = 0.f, acc1 = 0.f;
        if (nnz <= DCAP) {
#pragma unroll 4
            for (int t = 0; t < nnz; ++t) {
                int j = idxb[t];
                float pj = pbuf[j];
                const float* hr = h + (size_t)j * 512;
                acc0 += pj * hr[c];
                acc1 += pj * hr[c + 256];
            }
        } else {
            for (int j = 0; j < NNODES; ++j) {
                float pj = pbuf[j];
                if (pj > 0.f) {
                    const float* hr = h + (size_t)j * 512;
                    acc0 += pj * hr[c];
                    acc1 += pj * hr[c + 256];
                }
            }
        }
        float r0 = acc0 * inv, r1 = acc1 * inv;
        out[(size_t)i * 512 + c]       = r0 > 0.f ? r0 : expm1f(r0);
        out[(size_t)i * 512 + c + 256] = r1 > 0.f ? r1 : expm1f(r1);
    } else {
        const int half = tid >> 7;
        const int c = tid & 127;
        float acc = 0.f;
        if (nnz <= DCAP) {
#pragma unroll 4
            for (int t = half; t < nnz; t += 2) {
                int j = idxb[t];
                acc += pbuf[j] * h[(size_t)j * 128 + c];
            }
        } else {
            for (int j = half; j < NNODES; j += 2) {
                float pj = pbuf[j];
                if (pj > 0.f) acc += pj * h[(size_t)j * 128 + c];
            }
        }
        __syncthreads();
        pbuf[tid] = acc;
        __syncthreads();
        if (tid < 128) {
            float r = (pbuf[tid] + pbuf[tid + 128]) * inv;
            out[(size_t)i * 128 + tid] = r > 0.f ? r : expm1f(r);
        }
    }
}

// ---------------------------------------------------------------------------
// f32 apred fallback
// ---------------------------------------------------------------------------
__global__ __launch_bounds__(256) void apred_kernel(const float* __restrict__ z,
                                                    float* __restrict__ out)
{
    __shared__ float sA[32][68];
    __shared__ float sB[32][68];

    const int tid = threadIdx.x;
    const int tx = tid & 15, ty = tid >> 4;
    const int bm = blockIdx.x * 64, bn = blockIdx.y * 64;

    float acc[4][4] = {};

    for (int k0 = 0; k0 < 128; k0 += 32) {
        for (int l = tid; l < 64 * 32; l += 256) {
            int r = l >> 5, kk = l & 31;
            sA[kk][r] = z[(size_t)(bm + r) * 128 + k0 + kk];
            sB[kk][r] = z[(size_t)(bn + r) * 128 + k0 + kk];
        }
        __syncthreads();
#pragma unroll
        for (int kk = 0; kk < 32; ++kk) {
            float a[4], b[4];
#pragma unroll
            for (int i = 0; i < 4; ++i) a[i] = sA[kk][ty * 4 + i];
#pragma unroll
            for (int j = 0; j < 4; ++j) b[j] = sB[kk][tx * 4 + j];
#pragma unroll
            for (int i = 0; i < 4; ++i)
#pragma unroll
                for (int j = 0; j < 4; ++j) acc[i][j] += a[i] * b[j];
        }
        __syncthreads();
    }

#pragma unroll
    for (int i = 0; i < 4; ++i) {
        float4 v;
        v.x = 1.0f / (1.0f + expf(-acc[i][0]));
        v.y = 1.0f / (1.0f + expf(-acc[i][1]));
        v.z = 1.0f / (1.0f + expf(-acc[i][2]));
        v.w = 1.0f / (1.0f + expf(-acc[i][3]));
        *(float4*)&out[(size_t)(bm + ty * 4 + i) * NNODES + bn + tx * 4] = v;
    }
}

// ---------------------------------------------------------------------------
extern "C" void kernel_launch(void* const* d_in, const int* in_sizes, int n_in,
                              void* d_out, int out_size, void* d_ws, size_t ws_size,
                              hipStream_t stream)
{
    const float* x   = (const float*)d_in[0];
    const float* adj = (const float*)d_in[1];
    const float* Mm  = (const float*)d_in[2];
    const float* W1  = (const float*)d_in[3];
    const float* as1 = (const float*)d_in[4];
    const float* an1 = (const float*)d_in[5];
    const float* W2  = (const float*)d_in[6];
    const float* as2 = (const float*)d_in[7];
    const float* an2 = (const float*)d_in[8];

    float* out   = (float*)d_out;
    float* Apred = out;
    float* z     = out + (size_t)NNODES * NNODES;

    ushort_t* P    = (ushort_t*)Apred;                               // 128 MiB
    ushort_t* hbT  = (ushort_t*)((char*)Apred + (size_t)134217728);  // 8 MiB
    float*    part = (float*)((char*)Apred + (size_t)142606336);     // 64 MiB

    float* ws  = (float*)d_ws;
    float* h1  = ws;
    float* h1p = h1 + (size_t)NNODES * 512;
    float* h2p = h1p + (size_t)NNODES * 512;
    float* sv  = h2p + (size_t)NNODES * 128;
    float* nv  = sv + NNODES;
    float* vals = nv + NNODES;
    unsigned short* cols = (unsigned short*)(vals + (size_t)NNODES * CAP);
    int* nnzs = (int*)(cols + (size_t)NNODES * CAP);
    ushort_t* zb  = (ushort_t*)(nnzs + NNODES);
    ushort_t* h2b = zb + (size_t)NNODES * 128;
    ushort_t* xb  = h2b + (size_t)NNODES * 128;
    ushort_t* W1T = xb + (size_t)NNODES * 512;

    const size_t need = (size_t)((char*)(W1T + 512 * 512) - (char*)d_ws);

    if (ws_size >= need) {
        // layer 1: h1 = x @ W1 (bf16 MFMA)
        cast_bf<<<dim3(4096), 256, 0, stream>>>(x, xb, NNODES * 512 / 4);
        tcast<<<dim3(8, 8), 256, 0, stream>>>(W1, W1T, 512, 512);
        gemm_mfma<0><<<dim3(64, 4), 256, 0, stream>>>(xb, W1T, h1, 512, 512);
        sn_kernel<512><<<dim3(2048), 256, 0, stream>>>(h1, as1, an1, sv, nv);

        // sparsity path
        build_cols<<<dim3(2048), 256, 0, stream>>>(adj, cols, nnzs);
        gather_vals<<<dim3(NNODES), 256, 0, stream>>>(cols, Mm, nnzs, vals);
        softmax_dense<<<dim3(NNODES), 256, 0, stream>>>(cols, vals, nnzs, sv, nv, P);

        tcast<<<dim3(128, 8), 256, 0, stream>>>(h1, hbT, NNODES, 512);
        gemm_pv_ksplit<<<dim3(64, 4, KSPLIT), 256, 0, stream>>>(P, hbT, part);
        reduce_elu<<<dim3(NNODES * 512 / 4 / 256), 256, 0, stream>>>(part, h1p);

        // layer 2 (f32 gemm protects the z path)
        gemm64<<<dim3(128, 2), 256, 0, stream>>>(h1p, W2, h1, NNODES, 128, 512);
        sn128_fused<<<dim3(2048), 256, 0, stream>>>(h1, as2, an2, sv, nv, h2b);
        attn2_csr<<<dim3(NNODES), 256, 0, stream>>>(cols, vals, nnzs, sv, nv, h2b, h2p);

        // decoder
        norm_kernel<<<dim3(2048), 256, 0, stream>>>(h2p, z, zb);
        apred_mfma<<<dim3(64, 64), 256, 0, stream>>>(zb, Apred);
    } else {
        // fallback: round-1 dense f32 path
        gemm64<<<dim3(128, 8), 256, 0, stream>>>(x, W1, h1, NNODES, 512, 512);
        sn_kernel<512><<<dim3(2048), 256, 0, stream>>>(h1, as1, an1, sv, nv);
        attn_kernel<512><<<dim3(NNODES), 256, 0, stream>>>(adj, Mm, sv, nv, h1, h1p);

        gemm64<<<dim3(128, 2), 256, 0, stream>>>(h1p, W2, h1, NNODES, 128, 512);
        sn_kernel<128><<<dim3(2048), 256, 0, stream>>>(h1, as2, an2, sv, nv);
        attn_kernel<128><<<dim3(NNODES), 256, 0, stream>>>(adj, Mm, sv, nv, h1, h2p);

        norm_kernel<<<dim3(2048), 256, 0, stream>>>(h2p, z, zb);
        apred_kernel<<<dim3(128, 128), 256, 0, stream>>>(z, Apred);
    }
}

// Round 14
// 554.537 us; speedup vs baseline: 1.0191x; 1.0191x over previous
//
#include <hip/hip_runtime.h>
#include <math.h>

#define NNODES 8192
#define CAP 1024   // max neighbors/row in CSR (true max ~500 at 5% density)
#define KSPLIT 4
#define KCHUNK (NNODES / KSPLIT)

typedef __attribute__((ext_vector_type(8))) short bf16x8;
typedef __attribute__((ext_vector_type(4))) float f32x4;
typedef unsigned short ushort_t;

__device__ inline unsigned short f2bf(float x) {
    unsigned u = __builtin_bit_cast(unsigned, x);
    u += 0x7fffu + ((u >> 16) & 1u);   // RNE
    return (unsigned short)(u >> 16);
}

#define GLOAD_LDS16(g, l)                                                      \
    __builtin_amdgcn_global_load_lds(                                          \
        (const __attribute__((address_space(1))) void*)(g),                    \
        (__attribute__((address_space(3))) void*)(l), 16, 0, 0)

// Stage a [ROWS][64]-bf16 tile into LDS, XOR-swizzled via global src.
template <int ROWS>
__device__ inline void stage_tile(ushort_t* lds, const ushort_t* g, size_t ld, int tid)
{
#pragma unroll
    for (int c = 0; c < ROWS / 32; ++c) {
        int row = c * 32 + (tid >> 3);
        int lch = (tid & 7) ^ (row & 7);
        GLOAD_LDS16(g + (size_t)row * ld + lch * 8, lds + (size_t)c * 2048 + tid * 8);
    }
}

__device__ inline int swz_off(int row, int kc) {
    return row * 64 + ((kc ^ (row & 7)) * 8);
}

// ---------------------------------------------------------------------------
// f32 tiled GEMM (layer-2 h1p@W2 only)
// ---------------------------------------------------------------------------
__global__ __launch_bounds__(256) void gemm64(const float* __restrict__ A,
                                              const float* __restrict__ B,
                                              float* __restrict__ C,
                                              int M, int N, int K)
{
    __shared__ float sA[16][68];
    __shared__ float sB[16][68];

    const int tid = threadIdx.x;
    const int tx = tid & 15, ty = tid >> 4;
    const int bm = blockIdx.x * 64, bn = blockIdx.y * 64;

    float acc[4][4] = {};

    for (int k0 = 0; k0 < K; k0 += 16) {
        for (int l = tid; l < 64 * 16; l += 256) {
            int m = l >> 4, k = l & 15;
            sA[k][m] = A[(size_t)(bm + m) * K + k0 + k];
        }
        for (int l = tid; l < 16 * 64; l += 256) {
            int k = l >> 6, n = l & 63;
            sB[k][n] = B[(size_t)(k0 + k) * N + bn + n];
        }
        __syncthreads();
#pragma unroll
        for (int k = 0; k < 16; ++k) {
            float a[4], b[4];
#pragma unroll
            for (int i = 0; i < 4; ++i) a[i] = sA[k][ty * 4 + i];
#pragma unroll
            for (int j = 0; j < 4; ++j) b[j] = sB[k][tx * 4 + j];
#pragma unroll
            for (int i = 0; i < 4; ++i)
#pragma unroll
                for (int j = 0; j < 4; ++j) acc[i][j] += a[i] * b[j];
        }
        __syncthreads();
    }

#pragma unroll
    for (int i = 0; i < 4; ++i) {
        float4 v = make_float4(acc[i][0], acc[i][1], acc[i][2], acc[i][3]);
        *(float4*)&C[(size_t)(bm + ty * 4 + i) * N + bn + tx * 4] = v;
    }
}

// ---------------------------------------------------------------------------
// s = h @ a_self, n = h @ a_neigh  (one wave per row) — layer 1 (D=512)
// ---------------------------------------------------------------------------
template <int D>
__global__ __launch_bounds__(256) void sn_kernel(const float* __restrict__ h,
                                                 const float* __restrict__ a_s,
                                                 const float* __restrict__ a_n,
                                                 float* __restrict__ sv,
                                                 float* __restrict__ nv)
{
    const int row = (blockIdx.x * 256 + threadIdx.x) >> 6;
    const int lane = threadIdx.x & 63;
    if (row >= NNODES) return;
    const float* hr = h + (size_t)row * D;
    float a0 = 0.f, a1 = 0.f;
#pragma unroll
    for (int k = lane; k < D; k += 64) {
        float hv = hr[k];
        a0 += hv * a_s[k];
        a1 += hv * a_n[k];
    }
#pragma unroll
    for (int o = 32; o; o >>= 1) {
        a0 += __shfl_down(a0, o);
        a1 += __shfl_down(a1, o);
    }
    if (lane == 0) { sv[row] = a0; nv[row] = a1; }
}

// ---------------------------------------------------------------------------
// Layer-2 sn + fused bf16 cast: reads each h row once, emits sv/nv AND h2b.
// ---------------------------------------------------------------------------
__global__ __launch_bounds__(256) void sn128_fused(const float* __restrict__ h,
                                                   const float* __restrict__ a_s,
                                                   const float* __restrict__ a_n,
                                                   float* __restrict__ sv,
                                                   float* __restrict__ nv,
                                                   ushort_t* __restrict__ h2b)
{
    const int row = (blockIdx.x * 256 + threadIdx.x) >> 6;
    const int lane = threadIdx.x & 63;
    if (row >= NNODES) return;
    const float* hr = h + (size_t)row * 128;
    float v0 = hr[lane], v1 = hr[lane + 64];
    h2b[(size_t)row * 128 + lane]      = f2bf(v0);
    h2b[(size_t)row * 128 + lane + 64] = f2bf(v1);
    float a0 = v0 * a_s[lane] + v1 * a_s[lane + 64];
    float a1 = v0 * a_n[lane] + v1 * a_n[lane + 64];
#pragma unroll
    for (int o = 32; o; o >>= 1) {
        a0 += __shfl_down(a0, o);
        a1 += __shfl_down(a1, o);
    }
    if (lane == 0) { sv[row] = a0; nv[row] = a1; }
}

// ---------------------------------------------------------------------------
// adj-ONLY scan. Wave per row, ballot compaction (scan wall frozen).
// ---------------------------------------------------------------------------
__global__ __launch_bounds__(256) void build_cols(const float* __restrict__ adj,
                                                  unsigned short* __restrict__ cols,
                                                  int* __restrict__ nnzs)
{
    const int lane = threadIdx.x & 63;
    const int row = blockIdx.x * 4 + (threadIdx.x >> 6);
    const float4* arow = (const float4*)(adj + (size_t)row * NNODES);
    const size_t base = (size_t)row * CAP;
    const unsigned long long below = (1ull << lane) - 1ull;

    int off = 0;
    for (int c4 = 0; c4 < NNODES / 4; c4 += 64) {
        float4 a = arow[c4 + lane];
#pragma unroll
        for (int e = 0; e < 4; ++e) {
            float ae = (&a.x)[e];
            unsigned long long mask = __ballot(ae > 0.f);
            if (ae > 0.f) {
                int pos = off + __popcll(mask & below);
                if (pos < CAP)
                    cols[base + pos] = (unsigned short)((c4 + lane) * 4 + e);
            }
            off += __popcll(mask);
        }
    }
    if (lane == 0) nnzs[row] = off;
}

// ---------------------------------------------------------------------------
// Standalone M-value gather: vals[i][k] = M[i, cols[i][k]]. TLP-rich.
// ---------------------------------------------------------------------------
__global__ __launch_bounds__(256) void gather_vals(const unsigned short* __restrict__ cols,
                                                   const float* __restrict__ Mm,
                                                   const int* __restrict__ nnzs,
                                                   float* __restrict__ vals)
{
    const int i = blockIdx.x;
    const int nnz = min(nnzs[i], CAP);
    const size_t base = (size_t)i * CAP;
    const size_t rowoff = (size_t)i * NNODES;
    for (int k = threadIdx.x; k < nnz; k += 256)
        vals[base + k] = Mm[rowoff + cols[base + k]];
}

// ---------------------------------------------------------------------------
// Row softmax on CSR; dense bf16 P row in LDS, coalesced stream-out.
// ---------------------------------------------------------------------------
__global__ __launch_bounds__(256) void softmax_dense(const unsigned short* __restrict__ cols,
                                                     const float* __restrict__ vals,
                                                     const int* __restrict__ nnzs,
                                                     const float* __restrict__ sv,
                                                     const float* __restrict__ nv,
                                                     ushort_t* __restrict__ P)
{
    constexpr int NT = 256;
    __shared__ ushort_t drow[NNODES];
    __shared__ unsigned short scol[CAP];
    __shared__ float sp[CAP];
    __shared__ float reds[4];
    __shared__ float fb;

    const int tid = threadIdx.x;
    const int i = blockIdx.x;
    const int nnz = min(nnzs[i], CAP);
    const float si = sv[i];
    const size_t base = (size_t)i * CAP;

#pragma unroll
    for (int k = 0; k < NNODES / 8 / NT; ++k)
        ((uint4*)drow)[k * NT + tid] = (uint4){0u, 0u, 0u, 0u};

    float lmax = -3.0e38f;
    for (int k = tid; k < nnz; k += NT) {
        unsigned short c = cols[base + k];
        float e = (si + nv[c]) * vals[base + k];
        e = e > 0.f ? e : 0.2f * e;
        scol[k] = c;
        sp[k] = e;
        lmax = fmaxf(lmax, e);
    }
#pragma unroll
    for (int o = 32; o; o >>= 1) lmax = fmaxf(lmax, __shfl_down(lmax, o));
    if ((tid & 63) == 0) reds[tid >> 6] = lmax;
    __syncthreads();
    if (tid == 0) fb = fmaxf(fmaxf(reds[0], reds[1]), fmaxf(reds[2], reds[3]));
    __syncthreads();
    const float m = fb;

    float lsum = 0.f;
    for (int k = tid; k < nnz; k += NT) {
        float p = expf(sp[k] - m);
        sp[k] = p;
        lsum += p;
    }
#pragma unroll
    for (int o = 32; o; o >>= 1) lsum += __shfl_down(lsum, o);
    if ((tid & 63) == 0) reds[tid >> 6] = lsum;
    __syncthreads();
    if (tid == 0) fb = reds[0] + reds[1] + reds[2] + reds[3];
    __syncthreads();
    const float inv = 1.0f / fb;

    for (int k = tid; k < nnz; k += NT)
        drow[scol[k]] = f2bf(sp[k] * inv);
    __syncthreads();

    uint4* dst = (uint4*)(P + (size_t)i * NNODES);
#pragma unroll
    for (int k = 0; k < NNODES / 8 / NT; ++k)
        dst[k * NT + tid] = ((const uint4*)drow)[k * NT + tid];
}

// ---------------------------------------------------------------------------
// Generic transpose-cast: in [R][C] f32 -> out [C][R] bf16.
// ---------------------------------------------------------------------------
__global__ __launch_bounds__(256) void tcast(const float* __restrict__ in,
                                             ushort_t* __restrict__ out,
                                             int R, int C)
{
    __shared__ ushort_t t[64][66];
    const int bi = blockIdx.x;
    const int bj = blockIdx.y;
    const int c = threadIdx.x & 63, r4 = threadIdx.x >> 6;
#pragma unroll
    for (int i = 0; i < 16; ++i) {
        int r = i * 4 + r4;
        t[r][c] = f2bf(in[(size_t)(bi * 64 + r) * C + bj * 64 + c]);
    }
    __syncthreads();
#pragma unroll
    for (int i = 0; i < 16; ++i) {
        int r = i * 4 + r4;
        out[(size_t)(bj * 64 + r) * R + bi * 64 + c] = t[c][r];
    }
}

// ---------------------------------------------------------------------------
// flat f32 -> bf16 cast (4 elems/thread) — layer-1 x only
// ---------------------------------------------------------------------------
__global__ __launch_bounds__(256) void cast_bf(const float* __restrict__ in,
                                               ushort_t* __restrict__ out, int n4)
{
    int i = blockIdx.x * 256 + threadIdx.x;
    if (i >= n4) return;
    float4 v = ((const float4*)in)[i];
    ushort_t o[4] = { f2bf(v.x), f2bf(v.y), f2bf(v.z), f2bf(v.w) };
    *(uint2*)&out[(size_t)i * 4] = *(uint2*)o;
}

// ---------------------------------------------------------------------------
// Generic bf16 MFMA GEMM (x@W1): C = A @ BT^T. BM=BN=128, BK=64.
// ---------------------------------------------------------------------------
template <int ELU>
__global__ __launch_bounds__(256) void gemm_mfma(const ushort_t* __restrict__ A,
                                                 const ushort_t* __restrict__ BT,
                                                 float* __restrict__ C,
                                                 int N, int K)
{
    __shared__ __align__(16) ushort_t At[128 * 64];
    __shared__ __align__(16) ushort_t Bt[128 * 64];

    const int tid = threadIdx.x;
    const int wid = tid >> 6, lane = tid & 63;
    const int wr = wid >> 1, wc = wid & 1;
    const int bm = blockIdx.x * 128;
    const int bn = blockIdx.y * 128;

    f32x4 acc[4][4] = {};

    for (int k0 = 0; k0 < K; k0 += 64) {
        stage_tile<128>(At, A + (size_t)bm * K + k0, K, tid);
        stage_tile<128>(Bt, BT + (size_t)bn * K + k0, K, tid);
        __syncthreads();
#pragma unroll
        for (int kk = 0; kk < 2; ++kk) {
            const int kc = kk * 4 + (lane >> 4);
            bf16x8 af[4], bfr[4];
#pragma unroll
            for (int m = 0; m < 4; ++m) {
                int r = wr * 64 + m * 16 + (lane & 15);
                af[m] = *(const bf16x8*)&At[swz_off(r, kc)];
            }
#pragma unroll
            for (int n = 0; n < 4; ++n) {
                int r = wc * 64 + n * 16 + (lane & 15);
                bfr[n] = *(const bf16x8*)&Bt[swz_off(r, kc)];
            }
#pragma unroll
            for (int m = 0; m < 4; ++m)
#pragma unroll
                for (int n = 0; n < 4; ++n)
                    acc[m][n] = __builtin_amdgcn_mfma_f32_16x16x32_bf16(af[m], bfr[n], acc[m][n], 0, 0, 0);
        }
        __syncthreads();
    }

#pragma unroll
    for (int m = 0; m < 4; ++m)
#pragma unroll
        for (int n = 0; n < 4; ++n)
#pragma unroll
            for (int r_ = 0; r_ < 4; ++r_) {
                int row = bm + wr * 64 + m * 16 + (lane >> 4) * 4 + r_;
                int col = bn + wc * 64 + n * 16 + (lane & 15);
                float v = acc[m][n][r_];
                if (ELU) v = v > 0.f ? v : expm1f(v);
                C[(size_t)row * N + col] = v;
            }
}

// ---------------------------------------------------------------------------
// Split-K PV GEMM (r12 BK=64 version — best measured; r13 2-phase reverted).
// Grid (64, 4, KSPLIT) = 1024 blocks -> 4 blocks/CU; implicit wave overlap
// across blocks hides staging (m114 mechanism).
// ---------------------------------------------------------------------------
__global__ __launch_bounds__(256) void gemm_pv_ksplit(const ushort_t* __restrict__ P,
                                                      const ushort_t* __restrict__ hbT,
                                                      float* __restrict__ part)
{
    __shared__ __align__(16) ushort_t At[128 * 64];
    __shared__ __align__(16) ushort_t Bt[128 * 64];

    const int tid = threadIdx.x;
    const int wid = tid >> 6, lane = tid & 63;
    const int wr = wid >> 1, wc = wid & 1;
    const int bm = blockIdx.x * 128;
    const int bn = blockIdx.y * 128;
    const int kz = blockIdx.z;

    f32x4 acc[4][4] = {};

    const int kbeg = kz * KCHUNK, kend = kbeg + KCHUNK;
    for (int k0 = kbeg; k0 < kend; k0 += 64) {
        stage_tile<128>(At, P + (size_t)bm * NNODES + k0, NNODES, tid);
        stage_tile<128>(Bt, hbT + (size_t)bn * NNODES + k0, NNODES, tid);
        __syncthreads();
#pragma unroll
        for (int kk = 0; kk < 2; ++kk) {
            const int kc = kk * 4 + (lane >> 4);
            bf16x8 af[4], bfr[4];
#pragma unroll
            for (int m = 0; m < 4; ++m) {
                int r = wr * 64 + m * 16 + (lane & 15);
                af[m] = *(const bf16x8*)&At[swz_off(r, kc)];
            }
#pragma unroll
            for (int n = 0; n < 4; ++n) {
                int r = wc * 64 + n * 16 + (lane & 15);
                bfr[n] = *(const bf16x8*)&Bt[swz_off(r, kc)];
            }
#pragma unroll
            for (int m = 0; m < 4; ++m)
#pragma unroll
                for (int n = 0; n < 4; ++n)
                    acc[m][n] = __builtin_amdgcn_mfma_f32_16x16x32_bf16(af[m], bfr[n], acc[m][n], 0, 0, 0);
        }
        __syncthreads();
    }

    float* dst = part + (size_t)kz * NNODES * 512;
#pragma unroll
    for (int m = 0; m < 4; ++m)
#pragma unroll
        for (int n = 0; n < 4; ++n)
#pragma unroll
            for (int r_ = 0; r_ < 4; ++r_) {
                int row = bm + wr * 64 + m * 16 + (lane >> 4) * 4 + r_;
                int col = bn + wc * 64 + n * 16 + (lane & 15);
                dst[(size_t)row * 512 + col] = acc[m][n][r_];
            }
}

// ---------------------------------------------------------------------------
// h1p = elu(sum_kz part[kz])  — 4 reads + 1 write, float4.
// ---------------------------------------------------------------------------
__global__ __launch_bounds__(256) void reduce_elu(const float* __restrict__ part,
                                                  float* __restrict__ out)
{
    const size_t S = (size_t)NNODES * 512 / 4;
    size_t i = (size_t)blockIdx.x * 256 + threadIdx.x;
    if (i >= S) return;
    const float4* p = (const float4*)part;
    float4 a = p[i], b = p[i + S], c = p[i + 2 * S], d = p[i + 3 * S];
    float4 r;
    r.x = a.x + b.x + c.x + d.x;
    r.y = a.y + b.y + c.y + d.y;
    r.z = a.z + b.z + c.z + d.z;
    r.w = a.w + b.w + c.w + d.w;
    r.x = r.x > 0.f ? r.x : expm1f(r.x);
    r.y = r.y > 0.f ? r.y : expm1f(r.y);
    r.z = r.z > 0.f ? r.z : expm1f(r.z);
    r.w = r.w > 0.f ? r.w : expm1f(r.w);
    ((float4*)out)[i] = r;
}

// ---------------------------------------------------------------------------
// A_pred = sigmoid(z @ z^T), symmetry-halved with coalesced mirrored emit.
// ---------------------------------------------------------------------------
__global__ __launch_bounds__(256) void apred_mfma(const ushort_t* __restrict__ zb,
                                                  float* __restrict__ out)
{
    const int bx = blockIdx.x, by = blockIdx.y;
    if (bx > by) return;

    __shared__ __align__(16) char smem[4 * 64 * 68 * 4];
    ushort_t* At = (ushort_t*)smem;
    ushort_t* Bt = (ushort_t*)(smem + 16384);

    const int tid = threadIdx.x;
    const int wid = tid >> 6, lane = tid & 63;
    const int wr = wid >> 1, wc = wid & 1;
    const int bm = bx * 128;
    const int bn = by * 128;

    f32x4 acc[4][4] = {};

#pragma unroll
    for (int k0 = 0; k0 < 128; k0 += 64) {
        stage_tile<128>(At, zb + (size_t)bm * 128 + k0, 128, tid);
        stage_tile<128>(Bt, zb + (size_t)bn * 128 + k0, 128, tid);
        __syncthreads();
#pragma unroll
        for (int kk = 0; kk < 2; ++kk) {
            const int kc = kk * 4 + (lane >> 4);
            bf16x8 af[4], bfr[4];
#pragma unroll
            for (int m = 0; m < 4; ++m) {
                int r = wr * 64 + m * 16 + (lane & 15);
                af[m] = *(const bf16x8*)&At[swz_off(r, kc)];
            }
#pragma unroll
            for (int n = 0; n < 4; ++n) {
                int r = wc * 64 + n * 16 + (lane & 15);
                bfr[n] = *(const bf16x8*)&Bt[swz_off(r, kc)];
            }
#pragma unroll
            for (int m = 0; m < 4; ++m)
#pragma unroll
                for (int n = 0; n < 4; ++n)
                    acc[m][n] = __builtin_amdgcn_mfma_f32_16x16x32_bf16(af[m], bfr[n], acc[m][n], 0, 0, 0);
        }
        __syncthreads();
    }

    float* cb = (float*)smem + (size_t)wid * 64 * 68;
#pragma unroll
    for (int m = 0; m < 4; ++m)
#pragma unroll
        for (int n = 0; n < 4; ++n)
#pragma unroll
            for (int r_ = 0; r_ < 4; ++r_) {
                int rl = m * 16 + (lane >> 4) * 4 + r_;
                int cl = n * 16 + (lane & 15);
                float v = acc[m][n][r_];
                cb[rl * 68 + cl] = 1.0f / (1.0f + expf(-v));
            }

    const int rowbase = bm + wr * 64;
    const int colbase = bn + wc * 64;

#pragma unroll
    for (int j = 0; j < 16; ++j) {
        int rl = j * 4 + (lane >> 4);
        int c4 = (lane & 15) * 4;
        float4 v = *(const float4*)&cb[rl * 68 + c4];
        *(float4*)&out[(size_t)(rowbase + rl) * NNODES + colbase + c4] = v;
    }

    if (bx < by) {
#pragma unroll
        for (int j = 0; j < 16; ++j) {
            int rl2 = j * 4 + (lane >> 4);
            int c4 = (lane & 15) * 4;
            float4 v;
            v.x = cb[(c4 + 0) * 68 + rl2];
            v.y = cb[(c4 + 1) * 68 + rl2];
            v.z = cb[(c4 + 2) * 68 + rl2];
            v.w = cb[(c4 + 3) * 68 + rl2];
            *(float4*)&out[(size_t)(colbase + rl2) * NNODES + rowbase + c4] = v;
        }
    }
}

// ---------------------------------------------------------------------------
// Layer-2 CSR attention: probs f32, PV gather from bf16 h table (2 MiB).
// ---------------------------------------------------------------------------
__global__ __launch_bounds__(256) void attn2_csr(const unsigned short* __restrict__ cols,
                                                 const float* __restrict__ vals,
                                                 const int* __restrict__ nnzs,
                                                 const float* __restrict__ sv,
                                                 const float* __restrict__ nv,
                                                 const ushort_t* __restrict__ h2b,
                                                 float* __restrict__ out)
{
    constexpr int NT = 256;
    __shared__ unsigned short scol[CAP];
    __shared__ float sp[CAP];
    __shared__ float reds[4];
    __shared__ float fb;
    __shared__ float2 part[NT];

    const int tid = threadIdx.x;
    const int i = blockIdx.x;
    const int nnz = min(nnzs[i], CAP);
    const float si = sv[i];
    const size_t base = (size_t)i * CAP;

    float lmax = -3.0e38f;
    for (int k = tid; k < nnz; k += NT) {
        unsigned short c = cols[base + k];
        float e = (si + nv[c]) * vals[base + k];
        e = e > 0.f ? e : 0.2f * e;
        scol[k] = c;
        sp[k] = e;
        lmax = fmaxf(lmax, e);
    }
#pragma unroll
    for (int o = 32; o; o >>= 1) lmax = fmaxf(lmax, __shfl_down(lmax, o));
    if ((tid & 63) == 0) reds[tid >> 6] = lmax;
    __syncthreads();
    if (tid == 0) fb = fmaxf(fmaxf(reds[0], reds[1]), fmaxf(reds[2], reds[3]));
    __syncthreads();
    const float m = fb;

    float lsum = 0.f;
    for (int k = tid; k < nnz; k += NT) {
        float p = expf(sp[k] - m);
        sp[k] = p;
        lsum += p;
    }
#pragma unroll
    for (int o = 32; o; o >>= 1) lsum += __shfl_down(lsum, o);
    if ((tid & 63) == 0) reds[tid >> 6] = lsum;
    __syncthreads();
    if (tid == 0) fb = reds[0] + reds[1] + reds[2] + reds[3];
    __syncthreads();
    const float inv = 1.0f / fb;

    const int g = tid >> 6, lane = tid & 63;
    float ax = 0.f, ay = 0.f;
    for (int k = g; k < nnz; k += 4) {
        float pj = sp[k];
        unsigned hv = *(const unsigned*)&h2b[(size_t)scol[k] * 128 + lane * 2];
        ax += pj * __builtin_bit_cast(float, hv << 16);
        ay += pj * __builtin_bit_cast(float, hv & 0xffff0000u);
    }
    part[tid] = make_float2(ax, ay);
    __syncthreads();
    if (tid < 64) {
        float2 r0 = part[tid], r1 = part[tid + 64], r2 = part[tid + 128], r3 = part[tid + 192];
        float vx = (r0.x + r1.x + r2.x + r3.x) * inv;
        float vy = (r0.y + r1.y + r2.y + r3.y) * inv;
        out[(size_t)i * 128 + tid * 2]     = vx > 0.f ? vx : expm1f(vx);
        out[(size_t)i * 128 + tid * 2 + 1] = vy > 0.f ? vy : expm1f(vy);
    }
}

// ---------------------------------------------------------------------------
// z = h / max(||h||,1e-12); also writes bf16 copy zb
// ---------------------------------------------------------------------------
__global__ __launch_bounds__(256) void norm_kernel(const float* __restrict__ h,
                                                   float* __restrict__ z,
                                                   ushort_t* __restrict__ zb)
{
    const int row = (blockIdx.x * 256 + threadIdx.x) >> 6;
    const int lane = threadIdx.x & 63;
    if (row >= NNODES) return;
    const float* hr = h + (size_t)row * 128;
    float v0 = hr[lane], v1 = hr[lane + 64];
    float ss = v0 * v0 + v1 * v1;
#pragma unroll
    for (int o = 32; o; o >>= 1) ss += __shfl_down(ss, o);
    ss = __shfl(ss, 0);
    float invn = 1.0f / fmaxf(sqrtf(ss), 1e-12f);
    float z0 = v0 * invn, z1 = v1 * invn;
    z[(size_t)row * 128 + lane]      = z0;
    z[(size_t)row * 128 + lane + 64] = z1;
    zb[(size_t)row * 128 + lane]      = f2bf(z0);
    zb[(size_t)row * 128 + lane + 64] = f2bf(z1);
}

// ---------------------------------------------------------------------------
// Fallback dense attention (round-1 path) — only if ws is too small.
// ---------------------------------------------------------------------------
template <int D>
__global__ __launch_bounds__(256) void attn_kernel(const float* __restrict__ adj,
                                                   const float* __restrict__ Mm,
                                                   const float* __restrict__ sv,
                                                   const float* __restrict__ nv,
                                                   const float* __restrict__ h,
                                                   float* __restrict__ out)
{
    constexpr int NT = 256;
    constexpr int DCAP = 2048;
    __shared__ float pbuf[NNODES];
    __shared__ int   idxb[DCAP];
    __shared__ int   cnts[NT];
    __shared__ float reds[4];
    __shared__ float fbcast;
    __shared__ int   totc;

    const int tid = threadIdx.x;
    const int i = blockIdx.x;
    const size_t rowoff = (size_t)i * NNODES;
    const float si = sv[i];

    float lmax = -3.0e38f;
    for (int j = tid; j < NNODES; j += NT) {
        float a = adj[rowoff + j];
        float val = -9.0e15f;
        if (a > 0.f) {
            float e = (si + nv[j]) * Mm[rowoff + j];
            val = e > 0.f ? e : 0.2f * e;
            lmax = fmaxf(lmax, val);
        }
        pbuf[j] = val;
    }
#pragma unroll
    for (int o = 32; o; o >>= 1) lmax = fmaxf(lmax, __shfl_down(lmax, o));
    if ((tid & 63) == 0) reds[tid >> 6] = lmax;
    __syncthreads();
    if (tid == 0) fbcast = fmaxf(fmaxf(reds[0], reds[1]), fmaxf(reds[2], reds[3]));
    __syncthreads();
    const float m = fbcast;

    float lsum = 0.f;
    int myc = 0;
    for (int j = tid; j < NNODES; j += NT) {
        float v = pbuf[j];
        float p = (v > -8.9e15f) ? expf(v - m) : 0.f;
        pbuf[j] = p;
        lsum += p;
        if (p > 0.f) myc++;
    }
#pragma unroll
    for (int o = 32; o; o >>= 1) lsum += __shfl_down(lsum, o);
    if ((tid & 63) == 0) reds[tid >> 6] = lsum;
    cnts[tid] = myc;
    __syncthreads();
    if (tid == 0) {
        fbcast = reds[0] + reds[1] + reds[2] + reds[3];
        int run = 0;
        for (int t = 0; t < NT; ++t) { int c = cnts[t]; cnts[t] = run; run += c; }
        totc = run;
    }
    __syncthreads();
    const float inv = 1.0f / fbcast;
    const int nnz = totc;

    if (nnz <= DCAP) {
        int off = cnts[tid];
        for (int j = tid; j < NNODES; j += NT)
            if (pbuf[j] > 0.f) idxb[off++] = j;
    }
    __syncthreads();

    if constexpr (D == 512) {
        const int c = tid;
        float acc0 = 0.f, acc1 = 0.f;
        if (nnz <= DCAP) {
#pragma unroll 4
            for (int t = 0; t < nnz; ++t) {
                int j = idxb[t];
                float pj = pbuf[j];
                const float* hr = h + (size_t)j * 512;
                acc0 += pj * hr[c];
                acc1 += pj * hr[c + 256];
            }
        } else {
            for (int j = 0; j < NNODES; ++j) {
                float pj = pbuf[j];
                if (pj > 0.f) {
                    const float* hr = h + (size_t)j * 512;
                    acc0 += pj * hr[c];
                    acc1 += pj * hr[c + 256];
                }
            }
        }
        float r0 = acc0 * inv, r1 = acc1 * inv;
        out[(size_t)i * 512 + c]       = r0 > 0.f ? r0 : expm1f(r0);
        out[(size_t)i * 512 + c + 256] = r1 > 0.f ? r1 : expm1f(r1);
    } else {
        const int half = tid >> 7;
        const int c = tid & 127;
        float acc = 0.f;
        if (nnz <= DCAP) {
#pragma unroll 4
            for (int t = half; t < nnz; t += 2) {
                int j = idxb[t];
                acc += pbuf[j] * h[(size_t)j * 128 + c];
            }
        } else {
            for (int j = half; j < NNODES; j += 2) {
                float pj = pbuf[j];
                if (pj > 0.f) acc += pj * h[(size_t)j * 128 + c];
            }
        }
        __syncthreads();
        pbuf[tid] = acc;
        __syncthreads();
        if (tid < 128) {
            float r = (pbuf[tid] + pbuf[tid + 128]) * inv;
            out[(size_t)i * 128 + tid] = r > 0.f ? r : expm1f(r);
        }
    }
}

// ---------------------------------------------------------------------------
// f32 apred fallback
// ---------------------------------------------------------------------------
__global__ __launch_bounds__(256) void apred_kernel(const float* __restrict__ z,
                                                    float* __restrict__ out)
{
    __shared__ float sA[32][68];
    __shared__ float sB[32][68];

    const int tid = threadIdx.x;
    const int tx = tid & 15, ty = tid >> 4;
    const int bm = blockIdx.x * 64, bn = blockIdx.y * 64;

    float acc[4][4] = {};

    for (int k0 = 0; k0 < 128; k0 += 32) {
        for (int l = tid; l < 64 * 32; l += 256) {
            int r = l >> 5, kk = l & 31;
            sA[kk][r] = z[(size_t)(bm + r) * 128 + k0 + kk];
            sB[kk][r] = z[(size_t)(bn + r) * 128 + k0 + kk];
        }
        __syncthreads();
#pragma unroll
        for (int kk = 0; kk < 32; ++kk) {
            float a[4], b[4];
#pragma unroll
            for (int i = 0; i < 4; ++i) a[i] = sA[kk][ty * 4 + i];
#pragma unroll
            for (int j = 0; j < 4; ++j) b[j] = sB[kk][tx * 4 + j];
#pragma unroll
            for (int i = 0; i < 4; ++i)
#pragma unroll
                for (int j = 0; j < 4; ++j) acc[i][j] += a[i] * b[j];
        }
        __syncthreads();
    }

#pragma unroll
    for (int i = 0; i < 4; ++i) {
        float4 v;
        v.x = 1.0f / (1.0f + expf(-acc[i][0]));
        v.y = 1.0f / (1.0f + expf(-acc[i][1]));
        v.z = 1.0f / (1.0f + expf(-acc[i][2]));
        v.w = 1.0f / (1.0f + expf(-acc[i][3]));
        *(float4*)&out[(size_t)(bm + ty * 4 + i) * NNODES + bn + tx * 4] = v;
    }
}

// ---------------------------------------------------------------------------
extern "C" void kernel_launch(void* const* d_in, const int* in_sizes, int n_in,
                              void* d_out, int out_size, void* d_ws, size_t ws_size,
                              hipStream_t stream)
{
    const float* x   = (const float*)d_in[0];
    const float* adj = (const float*)d_in[1];
    const float* Mm  = (const float*)d_in[2];
    const float* W1  = (const float*)d_in[3];
    const float* as1 = (const float*)d_in[4];
    const float* an1 = (const float*)d_in[5];
    const float* W2  = (const float*)d_in[6];
    const float* as2 = (const float*)d_in[7];
    const float* an2 = (const float*)d_in[8];

    float* out   = (float*)d_out;
    float* Apred = out;
    float* z     = out + (size_t)NNODES * NNODES;

    ushort_t* P    = (ushort_t*)Apred;                               // 128 MiB
    ushort_t* hbT  = (ushort_t*)((char*)Apred + (size_t)134217728);  // 8 MiB
    float*    part = (float*)((char*)Apred + (size_t)142606336);     // 64 MiB

    float* ws  = (float*)d_ws;
    float* h1  = ws;
    float* h1p = h1 + (size_t)NNODES * 512;
    float* h2p = h1p + (size_t)NNODES * 512;
    float* sv  = h2p + (size_t)NNODES * 128;
    float* nv  = sv + NNODES;
    float* vals = nv + NNODES;
    unsigned short* cols = (unsigned short*)(vals + (size_t)NNODES * CAP);
    int* nnzs = (int*)(cols + (size_t)NNODES * CAP);
    ushort_t* zb  = (ushort_t*)(nnzs + NNODES);
    ushort_t* h2b = zb + (size_t)NNODES * 128;
    ushort_t* xb  = h2b + (size_t)NNODES * 128;
    ushort_t* W1T = xb + (size_t)NNODES * 512;

    const size_t need = (size_t)((char*)(W1T + 512 * 512) - (char*)d_ws);

    if (ws_size >= need) {
        // layer 1: h1 = x @ W1 (bf16 MFMA)
        cast_bf<<<dim3(4096), 256, 0, stream>>>(x, xb, NNODES * 512 / 4);
        tcast<<<dim3(8, 8), 256, 0, stream>>>(W1, W1T, 512, 512);
        gemm_mfma<0><<<dim3(64, 4), 256, 0, stream>>>(xb, W1T, h1, 512, 512);
        sn_kernel<512><<<dim3(2048), 256, 0, stream>>>(h1, as1, an1, sv, nv);

        // sparsity path
        build_cols<<<dim3(2048), 256, 0, stream>>>(adj, cols, nnzs);
        gather_vals<<<dim3(NNODES), 256, 0, stream>>>(cols, Mm, nnzs, vals);
        softmax_dense<<<dim3(NNODES), 256, 0, stream>>>(cols, vals, nnzs, sv, nv, P);

        tcast<<<dim3(128, 8), 256, 0, stream>>>(h1, hbT, NNODES, 512);
        gemm_pv_ksplit<<<dim3(64, 4, KSPLIT), 256, 0, stream>>>(P, hbT, part);
        reduce_elu<<<dim3(NNODES * 512 / 4 / 256), 256, 0, stream>>>(part, h1p);

        // layer 2 (f32 gemm protects the z path)
        gemm64<<<dim3(128, 2), 256, 0, stream>>>(h1p, W2, h1, NNODES, 128, 512);
        sn128_fused<<<dim3(2048), 256, 0, stream>>>(h1, as2, an2, sv, nv, h2b);
        attn2_csr<<<dim3(NNODES), 256, 0, stream>>>(cols, vals, nnzs, sv, nv, h2b, h2p);

        // decoder
        norm_kernel<<<dim3(2048), 256, 0, stream>>>(h2p, z, zb);
        apred_mfma<<<dim3(64, 64), 256, 0, stream>>>(zb, Apred);
    } else {
        // fallback: round-1 dense f32 path
        gemm64<<<dim3(128, 8), 256, 0, stream>>>(x, W1, h1, NNODES, 512, 512);
        sn_kernel<512><<<dim3(2048), 256, 0, stream>>>(h1, as1, an1, sv, nv);
        attn_kernel<512><<<dim3(NNODES), 256, 0, stream>>>(adj, Mm, sv, nv, h1, h1p);

        gemm64<<<dim3(128, 2), 256, 0, stream>>>(h1p, W2, h1, NNODES, 128, 512);
        sn_kernel<128><<<dim3(2048), 256, 0, stream>>>(h1, as2, an2, sv, nv);
        attn_kernel<128><<<dim3(NNODES), 256, 0, stream>>>(adj, Mm, sv, nv, h1, h2p);

        norm_kernel<<<dim3(2048), 256, 0, stream>>>(h2p, z, zb);
        apred_kernel<<<dim3(128, 128), 256, 0, stream>>>(z, Apred);
    }
}